// Round 5
// baseline (811.418 us; speedup 1.0000x reference)
//
#include <hip/hip_runtime.h>

#define D 128
#define CAP 64   // bucket capacity; degree ~Poisson(16); r>=CAP edges dropped (never fires)
typedef unsigned short u16;
typedef unsigned int   u32;

typedef __attribute__((ext_vector_type(8))) short short8;
typedef __attribute__((ext_vector_type(4))) float f32x4;

// ---- bf16 helpers (RNE) ----
__device__ __forceinline__ u32 f2bf(float f) {
    u32 u = __float_as_uint(f);
    u += 0x7fffu + ((u >> 16) & 1u);
    return u >> 16;
}
__device__ __forceinline__ float2 bf2x2(u32 u) {
    float2 r;
    r.x = __uint_as_float(u << 16);
    r.y = __uint_as_float(u & 0xffff0000u);
    return r;
}

struct KParams {
    const float4* x;      uint2* xb;
    const float4* W1;     const float4* W2;
    uint2* wb1;           uint2* wb2;
    const int* src;       const int* dst;    const float* attr;
    int* counts;          u32* combo;
    u16* aggB;
    const float* b1;      const float* b2;
    float* out;
    int* bar;             // 2 one-shot barrier slots (zeroed per launch)
    int* ticket;          // 3 work-stealing tickets (zeroed per launch)
    int E, n4, Nper, N, nBlocks;
};

// ---------------------------------------------------------------------------
// Hand-rolled grid barrier (one-shot slot). Correct in a PLAIN launch given
// all blocks co-resident: 1024 blocks @ 4/CU x 256 CU, guaranteed by
// __launch_bounds__(512,8) (VGPR<=64; r4 measured 60) + 8KB LDS (<=20/CU).
// Agent-scope atomics hit the cross-XCD coherence point; __threadfence()
// (agent acq_rel) publishes/acquires the non-atomic phase data.
// (cg::grid.sync() silently no-ops under the harness's graph capture --
//  round-2 failure.)
// ---------------------------------------------------------------------------
__device__ __forceinline__ void grid_barrier(int* slot, int nBlocks)
{
    __syncthreads();
    if (threadIdx.x == 0) {
        __threadfence();   // release this block's phase output
        __hip_atomic_fetch_add(slot, 1, __ATOMIC_ACQ_REL, __HIP_MEMORY_SCOPE_AGENT);
        while (__hip_atomic_load(slot, __ATOMIC_ACQUIRE, __HIP_MEMORY_SCOPE_AGENT)
               < nBlocks)
            __builtin_amdgcn_s_sleep(8);
        __threadfence();   // acquire before next phase
    }
    __syncthreads();
}

// ---------------------------------------------------------------------------
// Layer phase (round-1 proven inner loops). Tiles of 32 nodes are handed out
// by a work-stealing ticket (removes the ceil(1256/grid) imbalance that cost
// ~22% in r4's grid-stride). Per tile: 8 waves gather (sequential per-node,
// dwordx4 4-edge groups) into XOR-swizzled LDS, then MFMA gemm + relu.
//   Gather lane split: g = lane>>4 (edge slot), c16 = lane&15 (16B col).
//   GEMM C/D: col=lane&15, row=(lane>>4)*4+reg  [m89].
// ---------------------------------------------------------------------------
template <bool OUT_BF16>
__device__ __forceinline__ void layer_phase(
    u16* __restrict__ As, int* sWork, int* ticket,
    const u16* __restrict__ X,
    const u32* __restrict__ combo, const int* __restrict__ counts,
    const u16* __restrict__ Wb, const float* __restrict__ bias,
    void* __restrict__ Yv, int Nper, int N)
{
    const int tid  = threadIdx.x;
    const int w    = tid >> 6;        // wave 0..7
    const int lane = tid & 63;
    const int g    = lane >> 4;       // edge slot 0..3
    const int c16  = lane & 15;       // 16B slot within row
    const int nTiles = 8 * ((Nper + 31) / 32);   // 1256

    for (;;) {
        if (tid == 0)
            *sWork = (int)__hip_atomic_fetch_add(
                ticket, 1, __ATOMIC_RELAXED, __HIP_MEMORY_SCOPE_AGENT);
        __syncthreads();
        const int vt = *sWork;
        if (vt >= nTiles) return;     // uniform exit

        const int xcd   = vt & 7;
        const int slice = vt >> 3;
        const int nl0   = slice * 32 + w * 4;     // wave's first node (partition-local)
        const int nbase = xcd * Nper;             // partition base (global)

        // ---- preload descriptors for the wave's 4 nodes (coalesced) ----
        int cnt4[4]; u32 ce4[4];
        #pragma unroll
        for (int i = 0; i < 4; ++i) {
            int nl = nl0 + i;
            bool v = (nl < Nper) && (nbase + nl < N);
            cnt4[i] = v ? min(counts[nbase + nl], CAP) : 0;
            ce4[i]  = v ? combo[((long long)(nbase + nl) << 6) + lane] : 0u;
        }

        // ---- gather 4 nodes (sequential per node -- round-1 proven) ----
        #pragma unroll
        for (int i = 0; i < 4; ++i) {
            const int cnt = cnt4[i];
            const u32 ce  = ce4[i];
            float acc[8];
            #pragma unroll
            for (int c = 0; c < 8; ++c) acc[c] = 0.f;

            int j = 0;
            for (; j + 7 < cnt; j += 8) {         // 8 edges: 2 dwordx4 per lane
                u32 e0 = __shfl(ce, j + g);
                u32 e1 = __shfl(ce, j + 4 + g);
                uint4 r0 = *(const uint4*)(X + (long long)(e0 & 0xffffu) * D + c16 * 8);
                uint4 r1 = *(const uint4*)(X + (long long)(e1 & 0xffffu) * D + c16 * 8);
                float f0 = __uint_as_float(e0 & 0xffff0000u);
                float f1 = __uint_as_float(e1 & 0xffff0000u);
                float2 v;
                v = bf2x2(r0.x); acc[0] += v.x * f0; acc[1] += v.y * f0;
                v = bf2x2(r0.y); acc[2] += v.x * f0; acc[3] += v.y * f0;
                v = bf2x2(r0.z); acc[4] += v.x * f0; acc[5] += v.y * f0;
                v = bf2x2(r0.w); acc[6] += v.x * f0; acc[7] += v.y * f0;
                v = bf2x2(r1.x); acc[0] += v.x * f1; acc[1] += v.y * f1;
                v = bf2x2(r1.y); acc[2] += v.x * f1; acc[3] += v.y * f1;
                v = bf2x2(r1.z); acc[4] += v.x * f1; acc[5] += v.y * f1;
                v = bf2x2(r1.w); acc[6] += v.x * f1; acc[7] += v.y * f1;
            }
            for (; j + 3 < cnt; j += 4) {         // 4 edges
                u32 e0 = __shfl(ce, j + g);
                uint4 r0 = *(const uint4*)(X + (long long)(e0 & 0xffffu) * D + c16 * 8);
                float f0 = __uint_as_float(e0 & 0xffff0000u);
                float2 v;
                v = bf2x2(r0.x); acc[0] += v.x * f0; acc[1] += v.y * f0;
                v = bf2x2(r0.y); acc[2] += v.x * f0; acc[3] += v.y * f0;
                v = bf2x2(r0.z); acc[4] += v.x * f0; acc[5] += v.y * f0;
                v = bf2x2(r0.w); acc[6] += v.x * f0; acc[7] += v.y * f0;
            }
            {                                     // tail: rem in 0..3, group-masked
                int rem = cnt - j;
                u32 e0 = __shfl(ce, j + g);
                if (g < rem) {
                    uint4 r0 = *(const uint4*)(X + (long long)(e0 & 0xffffu) * D + c16 * 8);
                    float f0 = __uint_as_float(e0 & 0xffff0000u);
                    float2 v;
                    v = bf2x2(r0.x); acc[0] += v.x * f0; acc[1] += v.y * f0;
                    v = bf2x2(r0.y); acc[2] += v.x * f0; acc[3] += v.y * f0;
                    v = bf2x2(r0.z); acc[4] += v.x * f0; acc[5] += v.y * f0;
                    v = bf2x2(r0.w); acc[6] += v.x * f0; acc[7] += v.y * f0;
                }
            }

            // reduce the 4 edge slots (lanes l, l+16, l+32, l+48)
            #pragma unroll
            for (int c = 0; c < 8; ++c) {
                acc[c] += __shfl_xor(acc[c], 16);
                acc[c] += __shfl_xor(acc[c], 32);
            }

            if (g == 0) {                         // one slot stores the bf16 row
                uint4 o;
                o.x = f2bf(acc[0]) | (f2bf(acc[1]) << 16);
                o.y = f2bf(acc[2]) | (f2bf(acc[3]) << 16);
                o.z = f2bf(acc[4]) | (f2bf(acc[5]) << 16);
                o.w = f2bf(acc[6]) | (f2bf(acc[7]) << 16);
                int rowi = w * 4 + i;             // 0..31
                int slot = c16 ^ (rowi & 7);      // XOR swizzle (bijective per row)
                *(uint4*)&As[rowi * D + slot * 8] = o;
            }
        }

        __syncthreads();

        // ---- gemm: Y = relu(A @ W^T + b) ----
        const int mrow = lane & 15;
        const int kq   = lane >> 4;               // 0..3
        const int h    = w >> 2;                  // row half 0..1
        const int q    = w & 3;                   // col quarter 0..3
        const int lr0  = h * 16;

        short8 afr[4];
        const u16* asrc = As + (lr0 + mrow) * D;
        #pragma unroll
        for (int ks = 0; ks < 4; ++ks)
            afr[ks] = *(const short8*)(asrc + ((kq + ks * 4) ^ (mrow & 7)) * 8);

        #pragma unroll
        for (int jn = 0; jn < 2; ++jn) {
            const int n0 = q * 32 + jn * 16;
            float bv = bias[n0 + mrow];
            f32x4 acc2 = {bv, bv, bv, bv};
            const u16* wrow = Wb + (long long)(n0 + mrow) * D + kq * 8;
            #pragma unroll
            for (int ks = 0; ks < 4; ++ks) {
                short8 bfr = *(const short8*)(wrow + ks * 32);
                acc2 = __builtin_amdgcn_mfma_f32_16x16x32_bf16(afr[ks], bfr, acc2, 0, 0, 0);
            }
            #pragma unroll
            for (int r = 0; r < 4; ++r) {
                float v = acc2[r] > 0.f ? acc2[r] : 0.f;
                int lrow = lr0 + kq * 4 + r;
                int nl   = slice * 32 + lrow;
                if (nl < Nper && nbase + nl < N) {
                    long long off = (long long)(nbase + nl) * D + n0 + mrow;
                    if (OUT_BF16)
                        *((u16*)Yv + off) = (u16)f2bf(v);
                    else
                        *((float*)Yv + off) = v;
                }
            }
        }

        __syncthreads();   // protect As + sWork before next tile
    }
}

// ---------------------------------------------------------------------------
// Mega-kernel (PLAIN launch, 1024 blocks x 512 thr): P0 cvt | P1 hist+fill
// | bar | P2 layer1 | bar | P3 layer2.  launch_bounds(512,8) forces
// VGPR<=64 (r4: 60) -> 4 blocks/CU -> all 1024 co-resident (barrier-safe,
// ~94% occupancy vs r4's 47% at 512 blocks).  P1/P2/P3 are work-stealing
// (ticket atomics) -- no ceil-imbalance.  counts+bar+tickets zeroed by
// hipMemsetAsync.  P0|P1 need no barrier (disjoint data).
// ---------------------------------------------------------------------------
__global__ __launch_bounds__(512, 8) void mega_kernel(KParams P)
{
    __shared__ u16 As[32 * D];                // 8 KB
    __shared__ int sWork;

    const int tid = threadIdx.x;
    const int gsz = gridDim.x * 512;
    const int gt  = blockIdx.x * 512 + tid;

    // ---- P0: cvt x fp32->bf16; cvt W1,W2 ----
    for (int i = gt; i < P.n4; i += gsz) {
        float4 v = P.x[i];
        uint2 o;
        o.x = f2bf(v.x) | (f2bf(v.y) << 16);
        o.y = f2bf(v.z) | (f2bf(v.w) << 16);
        P.xb[i] = o;
    }
    for (int i = gt; i < 8192; i += gsz) {
        const float4* in = (i < 4096) ? P.W1 : P.W2;
        uint2* outw = (i < 4096) ? P.wb1 : P.wb2;
        int k = i & 4095;
        float4 v = in[k];
        uint2 o;
        o.x = f2bf(v.x) | (f2bf(v.y) << 16);
        o.y = f2bf(v.z) | (f2bf(v.w) << 16);
        outw[k] = o;
    }

    // ---- P1: XCD-partitioned hist+fill, work-stealing over 8x chunk passes ----
    {
        const int nWork = 8 * ((P.E + 2047) / 2048);
        for (;;) {
            if (tid == 0)
                sWork = (int)__hip_atomic_fetch_add(
                    &P.ticket[0], 1, __ATOMIC_RELAXED, __HIP_MEMORY_SCOPE_AGENT);
            __syncthreads();
            const int sb = sWork;
            if (sb >= nWork) break;   // uniform
            __syncthreads();          // all read sWork before next overwrite

            const int xcd   = sb & 7;
            const int chunk = sb >> 3;
            const int lo    = xcd * P.Nper;
            const int hi    = min(lo + P.Nper, P.N);
            long long e0 = (long long)chunk * 2048 + tid * 4;

            if (e0 + 3 < P.E) {
                int4   s4 = *(const int4*)(P.src + e0);
                int4   d4 = *(const int4*)(P.dst + e0);
                float4 a4 = *(const float4*)(P.attr + e0);
                #pragma unroll
                for (int q = 0; q < 4; ++q) {
                    int d = (q == 0) ? d4.x : (q == 1) ? d4.y : (q == 2) ? d4.z : d4.w;
                    if (d >= lo && d < hi) {
                        int s = (q == 0) ? s4.x : (q == 1) ? s4.y : (q == 2) ? s4.z : s4.w;
                        float a = (q == 0) ? a4.x : (q == 1) ? a4.y : (q == 2) ? a4.z : a4.w;
                        int r = atomicAdd(&P.counts[d], 1);
                        if (r < CAP)
                            P.combo[((long long)d << 6) + r] =
                                (u32)s | (f2bf(1.0f / a) << 16);
                    }
                }
            } else {
                for (int q = 0; q < 4; ++q) {
                    long long e = e0 + q;
                    if (e < P.E) {
                        int d = P.dst[e];
                        if (d >= lo && d < hi) {
                            int r = atomicAdd(&P.counts[d], 1);
                            if (r < CAP)
                                P.combo[((long long)d << 6) + r] =
                                    (u32)P.src[e] | (f2bf(1.0f / P.attr[e]) << 16);
                        }
                    }
                }
            }
        }
    }
    grid_barrier(&P.bar[0], P.nBlocks);   // xb/wb/combo/counts -> visible

    // ---- P2: layer 1 (xb -> aggB, bf16) ----
    layer_phase<true>(As, &sWork, &P.ticket[1], (const u16*)P.xb,
                      P.combo, P.counts, (const u16*)P.wb1, P.b1,
                      P.aggB, P.Nper, P.N);
    grid_barrier(&P.bar[1], P.nBlocks);   // aggB -> visible

    // ---- P3: layer 2 (aggB -> out, fp32) ----
    layer_phase<false>(As, &sWork, &P.ticket[2], P.aggB,
                       P.combo, P.counts, (const u16*)P.wb2, P.b2,
                       P.out, P.Nper, P.N);
}

// ---------------------------------------------------------------------------
extern "C" void kernel_launch(void* const* d_in, const int* in_sizes, int n_in,
                              void* d_out, int out_size, void* d_ws, size_t ws_size,
                              hipStream_t stream)
{
    const float* x    = (const float*)d_in[0];
    const int*   eidx = (const int*)d_in[1];
    const float* attr = (const float*)d_in[2];
    const float* W1   = (const float*)d_in[3];
    const float* b1   = (const float*)d_in[4];
    const float* W2   = (const float*)d_in[5];
    const float* b2   = (const float*)d_in[6];

    const int N = in_sizes[0] / D;        // 40000
    const int E = in_sizes[2];            // 640000
    const int Nper = (N + 7) / 8;         // 5000: dst partition per XCD

    // ws layout (16B-aligned). combo = N*CAP*4B = 10.25MB.
    char* p = (char*)d_ws;
    u16*  xb    = (u16*)p;   p += ((size_t)N * D * 2 + 15) & ~15ULL;
    u16*  aggB  = (u16*)p;   p += ((size_t)N * D * 2 + 15) & ~15ULL;
    u32*  combo = (u32*)p;   p += (size_t)N * CAP * 4;
    u16*  wb1   = (u16*)p;   p += (size_t)D * D * 2;
    u16*  wb2   = (u16*)p;   p += (size_t)D * D * 2;
    int*  counts= (int*)p;   p += (size_t)N * 4;
    int*  bar   = (int*)p;   p += 16;     // bar[0..1] (+pad)
    int*  ticket= (int*)p;   /* ticket[0..2] (+pad) */

    KParams P;
    P.x = (const float4*)x;  P.xb = (uint2*)xb;
    P.W1 = (const float4*)W1; P.W2 = (const float4*)W2;
    P.wb1 = (uint2*)wb1;     P.wb2 = (uint2*)wb2;
    P.src = eidx;            P.dst = eidx + E;     P.attr = attr;
    P.counts = counts;       P.combo = combo;
    P.aggB = aggB;
    P.b1 = b1;               P.b2 = b2;
    P.out = (float*)d_out;
    P.bar = bar;             P.ticket = ticket;
    P.E = E;  P.n4 = N * D / 4;  P.Nper = Nper;  P.N = N;
    P.nBlocks = 1024;

    // zero counts + barrier slots + tickets every launch
    hipMemsetAsync(counts, 0, (size_t)N * 4 + 32, stream);
    mega_kernel<<<1024, 512, 0, stream>>>(P);
}

// Round 6
// 186.112 us; speedup vs baseline: 4.3598x; 4.3598x over previous
//
#include <hip/hip_runtime.h>

#define D 128
#define CAP 64   // bucket capacity; degree ~Poisson(16); r>=CAP edges dropped (never fires)
typedef unsigned short u16;
typedef unsigned int   u32;

typedef __attribute__((ext_vector_type(8))) short short8;
typedef __attribute__((ext_vector_type(4))) float f32x4;

// ---- bf16 helpers (RNE) ----
__device__ __forceinline__ u32 f2bf(float f) {
    u32 u = __float_as_uint(f);
    u += 0x7fffu + ((u >> 16) & 1u);
    return u >> 16;
}
__device__ __forceinline__ float2 bf2x2(u32 u) {
    float2 r;
    r.x = __uint_as_float(u << 16);
    r.y = __uint_as_float(u & 0xffff0000u);
    return r;
}

// ---------------------------------------------------------------------------
// Fused prep (round-1 proven, verbatim): [0,cvtb): x fp32->bf16 ;
// [cvtb,cvtb+32): W1,W2->bf16 ; rest: XCD-PARTITIONED hist+fill.
// ---------------------------------------------------------------------------
__global__ __launch_bounds__(256) void prep_kernel(
    const float4* __restrict__ x, uint2* __restrict__ xb,
    const float4* __restrict__ W1, const float4* __restrict__ W2,
    uint2* __restrict__ wb1, uint2* __restrict__ wb2,
    const int* __restrict__ src, const int* __restrict__ dst,
    const float* __restrict__ attr, int* __restrict__ counts,
    u32* __restrict__ combo, int E, int n4, int cvtb, int Nper, int N)
{
    const int bid = blockIdx.x;
    const int t   = threadIdx.x;

    if (bid < cvtb) {                         // ---- cvt x ----
        int i = bid * 256 + t;
        if (i < n4) {
            float4 v = x[i];
            uint2 o;
            o.x = f2bf(v.x) | (f2bf(v.y) << 16);
            o.y = f2bf(v.z) | (f2bf(v.w) << 16);
            xb[i] = o;
        }
    } else if (bid < cvtb + 32) {             // ---- cvt W1,W2 ----
        int i = (bid - cvtb) * 256 + t;       // 0..8191
        const float4* in = (i < 4096) ? W1 : W2;
        uint2* out = (i < 4096) ? wb1 : wb2;
        int k = i & 4095;
        float4 v = in[k];
        uint2 o;
        o.x = f2bf(v.x) | (f2bf(v.y) << 16);
        o.y = f2bf(v.z) | (f2bf(v.w) << 16);
        out[k] = o;
    } else {                                  // ---- partitioned hist+fill ----
        const int sb    = bid - cvtb - 32;
        const int xcd   = sb & 7;             // target dst partition
        const int chunk = sb >> 3;
        const int lo    = xcd * Nper;
        const int hi    = min(lo + Nper, N);
        long long e0 = (long long)chunk * 1024 + t * 4;

        if (e0 + 3 < E) {
            int4   s4 = *(const int4*)(src + e0);
            int4   d4 = *(const int4*)(dst + e0);
            float4 a4 = *(const float4*)(attr + e0);
            #pragma unroll
            for (int q = 0; q < 4; ++q) {
                int d = (q == 0) ? d4.x : (q == 1) ? d4.y : (q == 2) ? d4.z : d4.w;
                if (d >= lo && d < hi) {
                    int s = (q == 0) ? s4.x : (q == 1) ? s4.y : (q == 2) ? s4.z : s4.w;
                    float a = (q == 0) ? a4.x : (q == 1) ? a4.y : (q == 2) ? a4.z : a4.w;
                    int r = atomicAdd(&counts[d], 1);
                    if (r < CAP)
                        combo[((long long)d << 6) + r] =
                            (u32)s | (f2bf(1.0f / a) << 16);
                }
            }
        } else {
            for (int q = 0; q < 4; ++q) {
                long long e = e0 + q;
                if (e < E) {
                    int d = dst[e];
                    if (d >= lo && d < hi) {
                        int r = atomicAdd(&counts[d], 1);
                        if (r < CAP)
                            combo[((long long)d << 6) + r] =
                                (u32)src[e] | (f2bf(1.0f / attr[e]) << 16);
                    }
                }
            }
        }
    }
}

// ---------------------------------------------------------------------------
// FUSED layer (round-1 structure; round-6 change: 16-edge unroll = FOUR
// independent dwordx4 per lane in flight, 64B/lane MLP vs 32B before;
// acc stays 8 regs, +16 VGPR for r[4] only -- no masked-load waste).
// Block = 512 thr = 8 waves, owns 32 nodes; gather -> XOR-swizzled LDS ->
// MFMA gemm -> relu -> store.
//   Gather lane split: g = lane>>4 (edge slot), c16 = lane&15 (16B col).
//   GEMM C/D: col=lane&15, row=(lane>>4)*4+reg  [m89].
// XCD-swizzled node assignment (blockIdx&7 = dst partition prep wrote from
// that XCD) keeps combo/counts reads L2-local.
// ---------------------------------------------------------------------------
template <bool OUT_BF16>
__global__ __launch_bounds__(512) void fused_layer_kernel(
    const u16* __restrict__ X, const u32* __restrict__ combo,
    const int* __restrict__ counts, const u16* __restrict__ Wb,
    const float* __restrict__ bias, void* __restrict__ Yv, int Nper, int N)
{
    __shared__ u16 As[32 * D];                // 8 KB, swizzled rows

    const int w    = threadIdx.x >> 6;        // wave 0..7
    const int lane = threadIdx.x & 63;
    const int g    = lane >> 4;               // edge slot 0..3
    const int c16  = lane & 15;               // 16B slot within row

    const int xcd   = blockIdx.x & 7;
    const int slice = blockIdx.x >> 3;
    const int nl0   = slice * 32 + w * 4;     // wave's first node (partition-local)
    const int nbase = xcd * Nper;             // partition base (global)

    // ---- preload descriptors for the wave's 4 nodes (coalesced) ----
    int cnt4[4]; u32 ce4[4];
    #pragma unroll
    for (int i = 0; i < 4; ++i) {
        int nl = nl0 + i;
        bool v = (nl < Nper) && (nbase + nl < N);
        cnt4[i] = v ? min(counts[nbase + nl], CAP) : 0;
        ce4[i]  = v ? combo[((long long)(nbase + nl) << 6) + lane] : 0u;
    }

    // ---- gather 4 nodes (sequential per node; deep load pipeline) ----
    #pragma unroll
    for (int i = 0; i < 4; ++i) {
        const int cnt = cnt4[i];
        const u32 ce  = ce4[i];
        float acc[8];
        #pragma unroll
        for (int c = 0; c < 8; ++c) acc[c] = 0.f;

        int j = 0;
        for (; j + 15 < cnt; j += 16) {       // 16 edges: 4 dwordx4/lane in flight
            u32 e0 = __shfl(ce, j + g);
            u32 e1 = __shfl(ce, j + 4 + g);
            u32 e2 = __shfl(ce, j + 8 + g);
            u32 e3 = __shfl(ce, j + 12 + g);
            uint4 r0 = *(const uint4*)(X + (long long)(e0 & 0xffffu) * D + c16 * 8);
            uint4 r1 = *(const uint4*)(X + (long long)(e1 & 0xffffu) * D + c16 * 8);
            uint4 r2 = *(const uint4*)(X + (long long)(e2 & 0xffffu) * D + c16 * 8);
            uint4 r3 = *(const uint4*)(X + (long long)(e3 & 0xffffu) * D + c16 * 8);
            float f0 = __uint_as_float(e0 & 0xffff0000u);
            float f1 = __uint_as_float(e1 & 0xffff0000u);
            float f2 = __uint_as_float(e2 & 0xffff0000u);
            float f3 = __uint_as_float(e3 & 0xffff0000u);
            float2 v;
            v = bf2x2(r0.x); acc[0] += v.x * f0; acc[1] += v.y * f0;
            v = bf2x2(r0.y); acc[2] += v.x * f0; acc[3] += v.y * f0;
            v = bf2x2(r0.z); acc[4] += v.x * f0; acc[5] += v.y * f0;
            v = bf2x2(r0.w); acc[6] += v.x * f0; acc[7] += v.y * f0;
            v = bf2x2(r1.x); acc[0] += v.x * f1; acc[1] += v.y * f1;
            v = bf2x2(r1.y); acc[2] += v.x * f1; acc[3] += v.y * f1;
            v = bf2x2(r1.z); acc[4] += v.x * f1; acc[5] += v.y * f1;
            v = bf2x2(r1.w); acc[6] += v.x * f1; acc[7] += v.y * f1;
            v = bf2x2(r2.x); acc[0] += v.x * f2; acc[1] += v.y * f2;
            v = bf2x2(r2.y); acc[2] += v.x * f2; acc[3] += v.y * f2;
            v = bf2x2(r2.z); acc[4] += v.x * f2; acc[5] += v.y * f2;
            v = bf2x2(r2.w); acc[6] += v.x * f2; acc[7] += v.y * f2;
            v = bf2x2(r3.x); acc[0] += v.x * f3; acc[1] += v.y * f3;
            v = bf2x2(r3.y); acc[2] += v.x * f3; acc[3] += v.y * f3;
            v = bf2x2(r3.z); acc[4] += v.x * f3; acc[5] += v.y * f3;
            v = bf2x2(r3.w); acc[6] += v.x * f3; acc[7] += v.y * f3;
        }
        for (; j + 7 < cnt; j += 8) {         // 8 edges: 2 dwordx4/lane
            u32 e0 = __shfl(ce, j + g);
            u32 e1 = __shfl(ce, j + 4 + g);
            uint4 r0 = *(const uint4*)(X + (long long)(e0 & 0xffffu) * D + c16 * 8);
            uint4 r1 = *(const uint4*)(X + (long long)(e1 & 0xffffu) * D + c16 * 8);
            float f0 = __uint_as_float(e0 & 0xffff0000u);
            float f1 = __uint_as_float(e1 & 0xffff0000u);
            float2 v;
            v = bf2x2(r0.x); acc[0] += v.x * f0; acc[1] += v.y * f0;
            v = bf2x2(r0.y); acc[2] += v.x * f0; acc[3] += v.y * f0;
            v = bf2x2(r0.z); acc[4] += v.x * f0; acc[5] += v.y * f0;
            v = bf2x2(r0.w); acc[6] += v.x * f0; acc[7] += v.y * f0;
            v = bf2x2(r1.x); acc[0] += v.x * f1; acc[1] += v.y * f1;
            v = bf2x2(r1.y); acc[2] += v.x * f1; acc[3] += v.y * f1;
            v = bf2x2(r1.z); acc[4] += v.x * f1; acc[5] += v.y * f1;
            v = bf2x2(r1.w); acc[6] += v.x * f1; acc[7] += v.y * f1;
        }
        for (; j + 3 < cnt; j += 4) {         // 4 edges
            u32 e0 = __shfl(ce, j + g);
            uint4 r0 = *(const uint4*)(X + (long long)(e0 & 0xffffu) * D + c16 * 8);
            float f0 = __uint_as_float(e0 & 0xffff0000u);
            float2 v;
            v = bf2x2(r0.x); acc[0] += v.x * f0; acc[1] += v.y * f0;
            v = bf2x2(r0.y); acc[2] += v.x * f0; acc[3] += v.y * f0;
            v = bf2x2(r0.z); acc[4] += v.x * f0; acc[5] += v.y * f0;
            v = bf2x2(r0.w); acc[6] += v.x * f0; acc[7] += v.y * f0;
        }
        {                                     // tail: rem in 0..3, group-masked
            int rem = cnt - j;
            u32 e0 = __shfl(ce, j + g);       // shfl reads regs irrespective of exec
            if (g < rem) {
                uint4 r0 = *(const uint4*)(X + (long long)(e0 & 0xffffu) * D + c16 * 8);
                float f0 = __uint_as_float(e0 & 0xffff0000u);
                float2 v;
                v = bf2x2(r0.x); acc[0] += v.x * f0; acc[1] += v.y * f0;
                v = bf2x2(r0.y); acc[2] += v.x * f0; acc[3] += v.y * f0;
                v = bf2x2(r0.z); acc[4] += v.x * f0; acc[5] += v.y * f0;
                v = bf2x2(r0.w); acc[6] += v.x * f0; acc[7] += v.y * f0;
            }
        }

        // reduce the 4 edge slots (lanes l, l+16, l+32, l+48)
        #pragma unroll
        for (int c = 0; c < 8; ++c) {
            acc[c] += __shfl_xor(acc[c], 16);
            acc[c] += __shfl_xor(acc[c], 32);
        }

        if (g == 0) {                         // one slot stores the bf16 row
            uint4 o;
            o.x = f2bf(acc[0]) | (f2bf(acc[1]) << 16);
            o.y = f2bf(acc[2]) | (f2bf(acc[3]) << 16);
            o.z = f2bf(acc[4]) | (f2bf(acc[5]) << 16);
            o.w = f2bf(acc[6]) | (f2bf(acc[7]) << 16);
            int rowi = w * 4 + i;             // 0..31
            int slot = c16 ^ (rowi & 7);      // XOR swizzle (bijective per row)
            *(uint4*)&As[rowi * D + slot * 8] = o;
        }
    }

    __syncthreads();

    // ---- gemm phase: Y = relu(A @ W^T + b) ----
    const int mrow = lane & 15;
    const int kq   = lane >> 4;               // 0..3
    const int h    = w >> 2;                  // row half 0..1
    const int q    = w & 3;                   // col quarter 0..3
    const int lr0  = h * 16;                  // tile's first local row

    short8 afr[4];
    const u16* asrc = As + (lr0 + mrow) * D;
    #pragma unroll
    for (int ks = 0; ks < 4; ++ks)
        afr[ks] = *(const short8*)(asrc + ((kq + ks * 4) ^ (mrow & 7)) * 8);

    #pragma unroll
    for (int jn = 0; jn < 2; ++jn) {
        const int n0 = q * 32 + jn * 16;
        float bv = bias[n0 + mrow];
        f32x4 acc2 = {bv, bv, bv, bv};
        const u16* wrow = Wb + (long long)(n0 + mrow) * D + kq * 8;
        #pragma unroll
        for (int ks = 0; ks < 4; ++ks) {
            short8 bfr = *(const short8*)(wrow + ks * 32);
            acc2 = __builtin_amdgcn_mfma_f32_16x16x32_bf16(afr[ks], bfr, acc2, 0, 0, 0);
        }
        #pragma unroll
        for (int r = 0; r < 4; ++r) {
            float v = acc2[r] > 0.f ? acc2[r] : 0.f;
            int lrow = lr0 + kq * 4 + r;      // local row 0..31
            int nl   = slice * 32 + lrow;     // partition-local node
            if (nl < Nper && nbase + nl < N) {
                long long off = (long long)(nbase + nl) * D + n0 + mrow;
                if (OUT_BF16)
                    *((u16*)Yv + off) = (u16)f2bf(v);
                else
                    *((float*)Yv + off) = v;
            }
        }
    }
}

// ---------------------------------------------------------------------------
// memset; prep; fused layer1 (xb -> aggB, bf16); fused layer2 (aggB -> d_out, fp32)
// ---------------------------------------------------------------------------
extern "C" void kernel_launch(void* const* d_in, const int* in_sizes, int n_in,
                              void* d_out, int out_size, void* d_ws, size_t ws_size,
                              hipStream_t stream)
{
    const float* x    = (const float*)d_in[0];
    const int*   eidx = (const int*)d_in[1];
    const float* attr = (const float*)d_in[2];
    const float* W1   = (const float*)d_in[3];
    const float* b1   = (const float*)d_in[4];
    const float* W2   = (const float*)d_in[5];
    const float* b2   = (const float*)d_in[6];

    const int N = in_sizes[0] / D;        // 40000
    const int E = in_sizes[2];            // 640000
    const int* src = eidx;
    const int* dst = eidx + E;
    const int Nper = (N + 7) / 8;         // 5000: dst partition per XCD

    // ws layout (16B-aligned). combo = N*CAP*4B = 10.25MB; ws ~268MB.
    char* p = (char*)d_ws;
    u16*  xb    = (u16*)p;   p += ((size_t)N * D * 2 + 15) & ~15ULL;
    u16*  aggB  = (u16*)p;   p += ((size_t)N * D * 2 + 15) & ~15ULL;
    u32*  combo = (u32*)p;   p += (size_t)N * CAP * 4;
    u16*  wb1   = (u16*)p;   p += (size_t)D * D * 2;
    u16*  wb2   = (u16*)p;   p += (size_t)D * D * 2;
    int*  counts= (int*)p;   /* p += N*4 */

    const int n4    = N * D / 4;                  // 1.28M
    const int cvtb  = (n4 + 255) / 256;           // 5000
    const int hfb   = 8 * ((E + 1023) / 1024);    // 5000 (8 XCD passes x 625 chunks)
    const int prepb = cvtb + 32 + hfb;            // 10032 (scatter offset 5032 == 0 mod 8)
    const int fusedb = 8 * ((Nper + 31) / 32);    // 1256 blocks x 512 thr

    hipMemsetAsync(counts, 0, (size_t)N * 4, stream);
    prep_kernel<<<prepb, 256, 0, stream>>>(
        (const float4*)x, (uint2*)xb, (const float4*)W1, (const float4*)W2,
        (uint2*)wb1, (uint2*)wb2, src, dst, attr, counts,
        combo, E, n4, cvtb, Nper, N);

    fused_layer_kernel<true><<<fusedb, 512, 0, stream>>>(
        xb, combo, counts, wb1, b1, aggB, Nper, N);
    fused_layer_kernel<false><<<fusedb, 512, 0, stream>>>(
        aggB, combo, counts, wb2, b2, d_out, Nper, N);
}